// Round 15
// baseline (148.540 us; speedup 1.0000x reference)
//
#include <hip/hip_runtime.h>
#include <hip/hip_bf16.h>

#define NTOK   4096
#define NBATCH 4
#define SPLIT  8

typedef short bf16x8 __attribute__((ext_vector_type(8)));
typedef float f32x4  __attribute__((ext_vector_type(4)));

static __device__ inline short f2bf(float x) {
    __hip_bfloat16 h = __float2bfloat16(x);
    return __builtin_bit_cast(short, h);
}
static __device__ inline float bf2f(short s) {
    return __bfloat162float(__builtin_bit_cast(__hip_bfloat16, s));
}
static __device__ inline f32x4 mfma16(bf16x8 a, bf16x8 b, f32x4 c) {
    return __builtin_amdgcn_mfma_f32_16x16x32_bf16(a, b, c, 0, 0, 0);
}

// ---------------------------------------------------------------------------
// Kernel A: patch embed + QKV projection + diagonal coefficient.
// 256 blocks x 512 thr (2 waves/SIMD). og = wave 0..7: 4 conv outputs,
// 12 proj outputs. Q/K written PACKED in MFMA fragment order:
//   p[((b*256 + n/16)*64 + (d/8)*16 + n%16)*8 + d%8]   (bf16 hi/lo)
// V fp32 token-major; coef[b*NTOK+n] = 1 - cos(2pi q.k) in fp32.
// ---------------------------------------------------------------------------
__global__ __launch_bounds__(512) void k_embed(
    const float* __restrict__ x,  const float* __restrict__ cw,
    const float* __restrict__ cb, const float* __restrict__ pw,
    const float* __restrict__ pb,
    short* __restrict__ qh, short* __restrict__ ql,
    short* __restrict__ kh, short* __restrict__ kl,
    float* __restrict__ vv, float* __restrict__ coef)
{
    __shared__ float tok_lds[64][33];
    __shared__ float qk_lds[64][65];   // [token][q0..31,k0..31]
    const int tid  = threadIdx.x;
    const int og   = tid >> 6;     // 0..7, wave-uniform
    const int tl   = tid & 63;
    const int bx   = blockIdx.x;
    const int b    = bx >> 6;
    const int hrow = bx & 63;
    const int n    = hrow * 64 + tl;

    float acc[4];
#pragma unroll
    for (int i = 0; i < 4; ++i) acc[i] = cb[og * 4 + i];

    const float* xb = x + (size_t)b * 3 * 512 * 512;
#pragma unroll
    for (int c = 0; c < 3; ++c) {
        float4 xr[16];
#pragma unroll
        for (int p = 0; p < 8; ++p) {
            const float* row = xb + ((size_t)c * 512 + hrow * 8 + p) * 512 + tl * 8;
            xr[p * 2]     = *(const float4*)row;
            xr[p * 2 + 1] = *(const float4*)(row + 4);
        }
#pragma unroll
        for (int oo = 0; oo < 4; ++oo) {
            const float* wrow = cw + ((size_t)(og * 4 + oo) * 3 + c) * 64;
            float s = 0.f;
#pragma unroll
            for (int j = 0; j < 16; ++j) {
                float4 wv = *(const float4*)(wrow + j * 4);
                s += xr[j].x * wv.x + xr[j].y * wv.y + xr[j].z * wv.z + xr[j].w * wv.w;
            }
            acc[oo] += s;
        }
    }
#pragma unroll
    for (int oo = 0; oo < 4; ++oo) tok_lds[tl][og * 4 + oo] = acc[oo];
    __syncthreads();
    float tok[32];
#pragma unroll
    for (int d = 0; d < 32; ++d) tok[d] = tok_lds[tl][d];

    const int toff = (b * NTOK + n) * 32;
    const int nch  = n >> 4, r16n = n & 15;
#pragma unroll
    for (int g2 = 0; g2 < 3; ++g2) {
        int jb = og * 12 + g2 * 4;
        float r[4];
#pragma unroll
        for (int l2 = 0; l2 < 4; ++l2) {
            int j = jb + l2;
            float s = pb[j];
            const float* prow = pw + j * 32;
#pragma unroll
            for (int d4 = 0; d4 < 8; ++d4) {
                float4 wv = *(const float4*)(prow + d4 * 4);
                s += tok[d4 * 4 + 0] * wv.x + tok[d4 * 4 + 1] * wv.y
                   + tok[d4 * 4 + 2] * wv.z + tok[d4 * 4 + 3] * wv.w;
            }
            r[l2] = s;
        }
        if (jb < 64) {
            // stage fp32 q,k for the diagonal dot
#pragma unroll
            for (int l2 = 0; l2 < 4; ++l2) qk_lds[tl][jb + l2] = r[l2];
            short hs[4], ls2[4];
#pragma unroll
            for (int l2 = 0; l2 < 4; ++l2) {
                hs[l2]  = f2bf(r[l2]);
                ls2[l2] = f2bf(r[l2] - bf2f(hs[l2]));
            }
            int off = (jb < 32) ? jb : (jb - 32);   // d within q or k row
            short* dh = (jb < 32) ? qh : kh;
            short* dl = (jb < 32) ? ql : kl;
            // packed fragment layout write
            size_t pa = ((size_t)(b * 256 + nch) * 64 + ((off >> 3) << 4) + r16n) * 8
                        + (off & 7);
            *(short4*)(dh + pa) = make_short4(hs[0], hs[1], hs[2], hs[3]);
            *(short4*)(dl + pa) = make_short4(ls2[0], ls2[1], ls2[2], ls2[3]);
        } else {
            *(float4*)(vv + toff + (jb - 64)) = make_float4(r[0], r[1], r[2], r[3]);
        }
    }
    __syncthreads();
    if (og == 0) {
        float dp = 0.f;
#pragma unroll
        for (int d = 0; d < 32; ++d) dp += qk_lds[tl][d] * qk_lds[tl][32 + d];
        coef[b * NTOK + n] = 1.f - __builtin_amdgcn_cosf(dp - floorf(dp));
    }
}

// ---------------------------------------------------------------------------
// Kernel B: build Varr — V in PV B-fragment lane order, hi/lo bf16.
// Layout per (b,chunk): 2048 shorts = [dt 2][hl 2][lane 64][slot 8].
// ---------------------------------------------------------------------------
__global__ __launch_bounds__(256) void k_varr(
    const float* __restrict__ vv, short* __restrict__ varr)
{
    __shared__ short lds[2048];
    const int tid = threadIdx.x;
    const int bx  = blockIdx.x;          // 512 blocks: b*128 + chunk
    const int b   = bx >> 7, c = bx & 127;
    const float* vb = vv + ((size_t)b * NTOK + c * 32) * 32;

    const int m  = tid >> 3;             // token in chunk 0..31
    const int d0 = (tid & 7) * 4;        // d base
    float4 v4 = *(const float4*)(vb + tid * 4);
    float vd[4] = {v4.x, v4.y, v4.z, v4.w};
#pragma unroll
    for (int l2 = 0; l2 < 4; ++l2) {
        int d = d0 + l2;
        int dt = d >> 4, r16 = d & 15;
        int g, j;
        if (m < 16) { g = m >> 2; j = m & 3; }
        else        { g = (m - 16) >> 2; j = 4 + ((m - 16) & 3); }
        int lane = g * 16 + r16;
        short hv = f2bf(vd[l2]);
        short lv = f2bf(vd[l2] - bf2f(hv));
        lds[dt * 1024 + 0 * 512 + lane * 8 + j] = hv;
        lds[dt * 1024 + 1 * 512 + lane * 8 + j] = lv;
    }
    __syncthreads();
    *(bf16x8*)(varr + ((size_t)b * 128 + c) * 2048 + tid * 8)
        = *(const bf16x8*)(lds + tid * 8);
}

// ---------------------------------------------------------------------------
// Kernel C: MFMA interference. All operand loads now DENSE b128 from packed
// layouts; epilogue transposed through LDS -> coalesced dwordx4 stores.
// ---------------------------------------------------------------------------
__global__ __launch_bounds__(256, 3) void k_attn(
    const short* __restrict__ qh, const short* __restrict__ ql,
    const short* __restrict__ kh, const short* __restrict__ kl,
    const short* __restrict__ varr, float* __restrict__ part)
{
    __shared__ float st[128][36];   // stride 36: 16B-aligned rows, 2-way banks
    const int t = threadIdx.x, l = t & 63, w = t >> 6;
    const int g = l >> 4, r16 = l & 15;
    const int bx = blockIdx.x;                 // 1024 blocks
    const int s = bx & 7, b = (bx >> 3) & 3, nb = bx >> 5;
    const int n0 = nb * 128 + w * 32;

    bf16x8 qfh[2], qfl[2];
#pragma unroll
    for (int nt = 0; nt < 2; ++nt) {
        size_t ro = ((size_t)(b * 256 + (n0 >> 4) + nt) * 64 + l) * 8;
        qfh[nt] = *(const bf16x8*)(qh + ro);
        qfl[nt] = *(const bf16x8*)(ql + ro);
    }
    f32x4 acc[2][2];
#pragma unroll
    for (int nt = 0; nt < 2; ++nt)
#pragma unroll
        for (int dt = 0; dt < 2; ++dt)
            acc[nt][dt] = (f32x4){0.f, 0.f, 0.f, 0.f};

    for (int ch = 0; ch < 16; ++ch) {
        const int mc = s * 512 + ch * 32;
        bf16x8 kfh[2], kfl[2];
#pragma unroll
        for (int mh = 0; mh < 2; ++mh) {
            size_t ro = ((size_t)(b * 256 + (mc >> 4) + mh) * 64 + l) * 8;
            kfh[mh] = *(const bf16x8*)(kh + ro);
            kfl[mh] = *(const bf16x8*)(kl + ro);
        }
        const short* vbase = varr + ((size_t)(b * 128 + (mc >> 5))) * 2048;
        bf16x8 vf00 = *(const bf16x8*)(vbase + l * 8);
        bf16x8 vf01 = *(const bf16x8*)(vbase + 512 + l * 8);
        bf16x8 vf10 = *(const bf16x8*)(vbase + 1024 + l * 8);
        bf16x8 vf11 = *(const bf16x8*)(vbase + 1536 + l * 8);

        bf16x8 pah[2], pal[2];
#pragma unroll
        for (int nt = 0; nt < 2; ++nt) {
            f32x4 sa = (f32x4){0.f, 0.f, 0.f, 0.f};
            f32x4 sb = (f32x4){0.f, 0.f, 0.f, 0.f};
            sa = mfma16(kfh[0], qfh[nt], sa);
            sa = mfma16(kfh[0], qfl[nt], sa);
            sa = mfma16(kfl[0], qfh[nt], sa);
            sb = mfma16(kfh[1], qfh[nt], sb);
            sb = mfma16(kfh[1], qfl[nt], sb);
            sb = mfma16(kfl[1], qfh[nt], sb);
#pragma unroll
            for (int r = 0; r < 4; ++r) {
                float xa = sa[r];
                float ca = __builtin_amdgcn_cosf(xa - floorf(xa));
                short ha = f2bf(ca);
                pah[nt][r] = ha;
                pal[nt][r] = f2bf(ca - bf2f(ha));
                float xb2 = sb[r];
                float cb2 = __builtin_amdgcn_cosf(xb2 - floorf(xb2));
                short hb = f2bf(cb2);
                pah[nt][r + 4] = hb;
                pal[nt][r + 4] = f2bf(cb2 - bf2f(hb));
            }
        }
#pragma unroll
        for (int nt = 0; nt < 2; ++nt) {
            acc[nt][0] = mfma16(pah[nt], vf00, acc[nt][0]);
            acc[nt][0] = mfma16(pah[nt], vf01, acc[nt][0]);
            acc[nt][0] = mfma16(pal[nt], vf00, acc[nt][0]);
            acc[nt][1] = mfma16(pah[nt], vf10, acc[nt][1]);
            acc[nt][1] = mfma16(pah[nt], vf11, acc[nt][1]);
            acc[nt][1] = mfma16(pal[nt], vf10, acc[nt][1]);
        }
    }
    // epilogue: transpose through LDS, then coalesced stores
#pragma unroll
    for (int nt = 0; nt < 2; ++nt)
#pragma unroll
        for (int dt = 0; dt < 2; ++dt)
#pragma unroll
            for (int r = 0; r < 4; ++r)
                st[w * 32 + nt * 16 + 4 * g + r][dt * 16 + r16] = acc[nt][dt][r];
    __syncthreads();
    const int tk = t >> 1, d0 = (t & 1) * 16;
    float* pbp = part + ((size_t)(s * NBATCH + b) * NTOK + nb * 128 + tk) * 32 + d0;
    const float* sp = &st[tk][d0];
#pragma unroll
    for (int q4 = 0; q4 < 4; ++q4)
        *(float4*)(pbp + q4 * 4) = *(const float4*)(sp + q4 * 4);
}

// ---------------------------------------------------------------------------
// Kernel R: inter = sum_s part[s] + coef * v. 512 blocks x 256 thr.
// ---------------------------------------------------------------------------
__global__ __launch_bounds__(256) void k_reduce(
    const float* __restrict__ part, const float* __restrict__ vv,
    const float* __restrict__ coef, float* __restrict__ inter)
{
    const int idx = blockIdx.x * 256 + threadIdx.x;   // 0..131071
    const int g = idx >> 3, d4 = idx & 7;
    const float* p0 = part + (size_t)g * 32 + d4 * 4;
    float4 s = make_float4(0.f, 0.f, 0.f, 0.f);
#pragma unroll
    for (int sp = 0; sp < SPLIT; ++sp) {
        float4 t = *(const float4*)(p0 + (size_t)sp * (NBATCH * NTOK * 32));
        s.x += t.x; s.y += t.y; s.z += t.z; s.w += t.w;
    }
    const float cf = coef[g];
    float4 v4 = *(const float4*)(vv + (size_t)g * 32 + d4 * 4);
    s.x += cf * v4.x; s.y += cf * v4.y; s.z += cf * v4.z; s.w += cf * v4.w;
    *(float4*)(inter + (size_t)g * 32 + d4 * 4) = s;
}

// ---------------------------------------------------------------------------
// Kernel D: ConvTranspose 8x8 stride 8. 256 blocks x 512 thr.
// ---------------------------------------------------------------------------
__global__ __launch_bounds__(512) void k_deconv(
    const float* __restrict__ inter, const float* __restrict__ dw,
    const float* __restrict__ db, float* __restrict__ out)
{
    const int tid  = threadIdx.x;
    const int wv   = tid >> 6;     // 0..7, wave-uniform
    const int lane = tid & 63;     // token w
    const int bx   = blockIdx.x;
    const int b    = bx >> 6;
    const int hrow = bx & 63;
    const int n    = hrow * 64 + lane;

    float ir[32];
    const float* ip = inter + ((size_t)(b * NTOK + n)) * 32;
#pragma unroll
    for (int d4 = 0; d4 < 8; ++d4) {
        float4 t4 = *(const float4*)(ip + d4 * 4);
        ir[d4 * 4 + 0] = t4.x; ir[d4 * 4 + 1] = t4.y;
        ir[d4 * 4 + 2] = t4.z; ir[d4 * 4 + 3] = t4.w;
    }
#pragma unroll
    for (int rr = 0; rr < 3; ++rr) {
        const int rho = wv * 3 + rr;      // 0..23, wave-uniform
        const int o = rho >> 3, p = rho & 7;
        const float bv = db[o];
        float a8[8];
#pragma unroll
        for (int q = 0; q < 8; ++q) a8[q] = bv;
        const float* wbase = dw + o * 64 + p * 8;
#pragma unroll
        for (int i = 0; i < 32; ++i) {
            float4 w0 = *(const float4*)(wbase + (size_t)i * 192);
            float4 w1 = *(const float4*)(wbase + (size_t)i * 192 + 4);
            const float iv = ir[i];
            a8[0] += iv * w0.x; a8[1] += iv * w0.y;
            a8[2] += iv * w0.z; a8[3] += iv * w0.w;
            a8[4] += iv * w1.x; a8[5] += iv * w1.y;
            a8[6] += iv * w1.z; a8[7] += iv * w1.w;
        }
        float* op = out + (((size_t)(b * 3 + o) * 512) + hrow * 8 + p) * 512 + lane * 8;
        *(float4*)op       = make_float4(a8[0], a8[1], a8[2], a8[3]);
        *(float4*)(op + 4) = make_float4(a8[4], a8[5], a8[6], a8[7]);
    }
}

// ---------------------------------------------------------------------------
extern "C" void kernel_launch(void* const* d_in, const int* in_sizes, int n_in,
                              void* d_out, int out_size, void* d_ws, size_t ws_size,
                              hipStream_t stream)
{
    const float* x  = (const float*)d_in[0];
    const float* cw = (const float*)d_in[1];
    const float* cb = (const float*)d_in[2];
    const float* pw = (const float*)d_in[3];
    const float* pb = (const float*)d_in[4];
    const float* dw = (const float*)d_in[5];
    const float* db = (const float*)d_in[6];
    float* out = (float*)d_out;

    char* wsb = (char*)d_ws;
    const size_t MB = 1u << 20;
    short* qh    = (short*)(wsb + 0 * MB);
    short* ql    = (short*)(wsb + 1 * MB);
    short* kh    = (short*)(wsb + 2 * MB);
    short* kl    = (short*)(wsb + 3 * MB);
    float* vv    = (float*)(wsb + 4 * MB);   // 2 MB
    short* varr  = (short*)(wsb + 6 * MB);   // 2 MB
    float* part  = (float*)(wsb + 8 * MB);   // 16 MB
    float* coef  = (float*)(wsb + 24 * MB);  // 64 KB
    float* inter = (float*)(wsb + 25 * MB);  // 2 MB

    hipLaunchKernelGGL(k_embed, dim3(256), dim3(512), 0, stream,
                       x, cw, cb, pw, pb, qh, ql, kh, kl, vv, coef);
    hipLaunchKernelGGL(k_varr, dim3(512), dim3(256), 0, stream, vv, varr);
    hipLaunchKernelGGL(k_attn, dim3(1024), dim3(256), 0, stream,
                       qh, ql, kh, kl, varr, part);
    hipLaunchKernelGGL(k_reduce, dim3(512), dim3(256), 0, stream,
                       part, vv, coef, inter);
    hipLaunchKernelGGL(k_deconv, dim3(256), dim3(512), 0, stream,
                       inter, dw, db, out);
}

// Round 16
// 143.885 us; speedup vs baseline: 1.0324x; 1.0324x over previous
//
#include <hip/hip_runtime.h>
#include <hip/hip_bf16.h>

#define NTOK   4096
#define NBATCH 4
#define SPLIT  8

typedef short bf16x8 __attribute__((ext_vector_type(8)));
typedef float f32x4  __attribute__((ext_vector_type(4)));

static __device__ inline short f2bf(float x) {
    __hip_bfloat16 h = __float2bfloat16(x);
    return __builtin_bit_cast(short, h);
}
static __device__ inline float bf2f(short s) {
    return __bfloat162float(__builtin_bit_cast(__hip_bfloat16, s));
}
static __device__ inline f32x4 mfma16(bf16x8 a, bf16x8 b, f32x4 c) {
    return __builtin_amdgcn_mfma_f32_16x16x32_bf16(a, b, c, 0, 0, 0);
}

// ---------------------------------------------------------------------------
// Kernel A: patch embed + QKV proj + diag coef + Varr build (k_varr fused).
// 256 blocks x 256 thr. og = wave 0..3: 8 conv outputs, 24 proj outputs.
// Q/K packed in MFMA fragment order:
//   p[((b*256 + n/16)*64 + (d/8)*16 + n%16)*8 + d%8]   (bf16 hi/lo)
// V fp32 token-major + staged in LDS -> Varr written directly (coalesced).
// ---------------------------------------------------------------------------
__global__ __launch_bounds__(256) void k_embed(
    const float* __restrict__ x,  const float* __restrict__ cw,
    const float* __restrict__ cb, const float* __restrict__ pw,
    const float* __restrict__ pb,
    short* __restrict__ qh, short* __restrict__ ql,
    short* __restrict__ kh, short* __restrict__ kl,
    float* __restrict__ vv, float* __restrict__ coef,
    short* __restrict__ varr)
{
    __shared__ float tok_lds[64][33];
    __shared__ float qk_lds[64][65];   // [token][q0..31,k0..31]
    __shared__ float v_lds[64][33];    // [token][v0..31]
    const int tid  = threadIdx.x;
    const int og   = tid >> 6;     // 0..3, wave-uniform
    const int tl   = tid & 63;
    const int bx   = blockIdx.x;
    const int b    = bx >> 6;
    const int hrow = bx & 63;
    const int n    = hrow * 64 + tl;

    float acc[8];
#pragma unroll
    for (int i = 0; i < 8; ++i) acc[i] = cb[og * 8 + i];

    const float* xb = x + (size_t)b * 3 * 512 * 512;
#pragma unroll
    for (int c = 0; c < 3; ++c) {
        float4 xr[16];
#pragma unroll
        for (int p = 0; p < 8; ++p) {
            const float* row = xb + ((size_t)c * 512 + hrow * 8 + p) * 512 + tl * 8;
            xr[p * 2]     = *(const float4*)row;
            xr[p * 2 + 1] = *(const float4*)(row + 4);
        }
#pragma unroll
        for (int oo = 0; oo < 8; ++oo) {
            const float* wrow = cw + ((size_t)(og * 8 + oo) * 3 + c) * 64;
            float s = 0.f;
#pragma unroll
            for (int j = 0; j < 16; ++j) {
                float4 wv = *(const float4*)(wrow + j * 4);
                s += xr[j].x * wv.x + xr[j].y * wv.y + xr[j].z * wv.z + xr[j].w * wv.w;
            }
            acc[oo] += s;
        }
    }
#pragma unroll
    for (int oo = 0; oo < 8; ++oo) tok_lds[tl][og * 8 + oo] = acc[oo];
    __syncthreads();
    float tok[32];
#pragma unroll
    for (int d = 0; d < 32; ++d) tok[d] = tok_lds[tl][d];

    const int toff = (b * NTOK + n) * 32;
    const int nch  = n >> 4, r16n = n & 15;
#pragma unroll
    for (int g2 = 0; g2 < 6; ++g2) {
        int jb = og * 24 + g2 * 4;
        float r[4];
#pragma unroll
        for (int l2 = 0; l2 < 4; ++l2) {
            int j = jb + l2;
            float s = pb[j];
            const float* prow = pw + j * 32;
#pragma unroll
            for (int d4 = 0; d4 < 8; ++d4) {
                float4 wv = *(const float4*)(prow + d4 * 4);
                s += tok[d4 * 4 + 0] * wv.x + tok[d4 * 4 + 1] * wv.y
                   + tok[d4 * 4 + 2] * wv.z + tok[d4 * 4 + 3] * wv.w;
            }
            r[l2] = s;
        }
        if (jb < 64) {
#pragma unroll
            for (int l2 = 0; l2 < 4; ++l2) qk_lds[tl][jb + l2] = r[l2];
            short hs[4], ls2[4];
#pragma unroll
            for (int l2 = 0; l2 < 4; ++l2) {
                hs[l2]  = f2bf(r[l2]);
                ls2[l2] = f2bf(r[l2] - bf2f(hs[l2]));
            }
            int off = (jb < 32) ? jb : (jb - 32);
            short* dh = (jb < 32) ? qh : kh;
            short* dl = (jb < 32) ? ql : kl;
            size_t pa = ((size_t)(b * 256 + nch) * 64 + ((off >> 3) << 4) + r16n) * 8
                        + (off & 7);
            *(short4*)(dh + pa) = make_short4(hs[0], hs[1], hs[2], hs[3]);
            *(short4*)(dl + pa) = make_short4(ls2[0], ls2[1], ls2[2], ls2[3]);
        } else {
            *(float4*)(vv + toff + (jb - 64)) = make_float4(r[0], r[1], r[2], r[3]);
#pragma unroll
            for (int l2 = 0; l2 < 4; ++l2) v_lds[tl][jb - 64 + l2] = r[l2];
        }
    }
    __syncthreads();
    if (og == 0) {
        float dp = 0.f;
#pragma unroll
        for (int d = 0; d < 32; ++d) dp += qk_lds[tl][d] * qk_lds[tl][32 + d];
        coef[b * NTOK + n] = 1.f - __builtin_amdgcn_cosf(dp - floorf(dp));
    }
    // ---- fused Varr build: block owns chunks 2*hrow, 2*hrow+1 ----
    {
        const int c_loc = tid >> 7;          // 0..1
        const int rr    = tid & 127;
        size_t vout = ((size_t)b * 128 + hrow * 2 + c_loc) * 2048;
#pragma unroll
        for (int gi2 = 0; gi2 < 2; ++gi2) {
            int gi = rr * 2 + gi2;           // 0..255: (dt,hl,lane)
            int dt = gi >> 7, hl = (gi >> 6) & 1, lane = gi & 63;
            int g = lane >> 4, r16 = lane & 15;
            bf16x8 outv;
#pragma unroll
            for (int j = 0; j < 8; ++j) {
                int m = (j < 4) ? (4 * g + j) : (16 + 4 * g + (j - 4));
                float xv = v_lds[c_loc * 32 + m][dt * 16 + r16];
                short hv = f2bf(xv);
                outv[j] = (hl == 0) ? hv : f2bf(xv - bf2f(hv));
            }
            *(bf16x8*)(varr + vout + (size_t)dt * 1024 + hl * 512 + lane * 8) = outv;
        }
    }
}

// ---------------------------------------------------------------------------
// Kernel C: MFMA interference. pal (P-low) x V product dropped: 20 MFMA/chunk.
// ---------------------------------------------------------------------------
__global__ __launch_bounds__(256, 3) void k_attn(
    const short* __restrict__ qh, const short* __restrict__ ql,
    const short* __restrict__ kh, const short* __restrict__ kl,
    const short* __restrict__ varr, float* __restrict__ part)
{
    __shared__ float st[128][36];
    const int t = threadIdx.x, l = t & 63, w = t >> 6;
    const int g = l >> 4, r16 = l & 15;
    const int bx = blockIdx.x;                 // 1024 blocks
    const int s = bx & 7, b = (bx >> 3) & 3, nb = bx >> 5;
    const int n0 = nb * 128 + w * 32;

    bf16x8 qfh[2], qfl[2];
#pragma unroll
    for (int nt = 0; nt < 2; ++nt) {
        size_t ro = ((size_t)(b * 256 + (n0 >> 4) + nt) * 64 + l) * 8;
        qfh[nt] = *(const bf16x8*)(qh + ro);
        qfl[nt] = *(const bf16x8*)(ql + ro);
    }
    f32x4 acc[2][2];
#pragma unroll
    for (int nt = 0; nt < 2; ++nt)
#pragma unroll
        for (int dt = 0; dt < 2; ++dt)
            acc[nt][dt] = (f32x4){0.f, 0.f, 0.f, 0.f};

    for (int ch = 0; ch < 16; ++ch) {
        const int mc = s * 512 + ch * 32;
        bf16x8 kfh[2], kfl[2];
#pragma unroll
        for (int mh = 0; mh < 2; ++mh) {
            size_t ro = ((size_t)(b * 256 + (mc >> 4) + mh) * 64 + l) * 8;
            kfh[mh] = *(const bf16x8*)(kh + ro);
            kfl[mh] = *(const bf16x8*)(kl + ro);
        }
        const short* vbase = varr + ((size_t)(b * 128 + (mc >> 5))) * 2048;
        bf16x8 vf00 = *(const bf16x8*)(vbase + l * 8);
        bf16x8 vf01 = *(const bf16x8*)(vbase + 512 + l * 8);
        bf16x8 vf10 = *(const bf16x8*)(vbase + 1024 + l * 8);
        bf16x8 vf11 = *(const bf16x8*)(vbase + 1536 + l * 8);

        bf16x8 pah[2];
#pragma unroll
        for (int nt = 0; nt < 2; ++nt) {
            f32x4 sa = (f32x4){0.f, 0.f, 0.f, 0.f};
            f32x4 sb = (f32x4){0.f, 0.f, 0.f, 0.f};
            sa = mfma16(kfh[0], qfh[nt], sa);
            sa = mfma16(kfh[0], qfl[nt], sa);
            sa = mfma16(kfl[0], qfh[nt], sa);
            sb = mfma16(kfh[1], qfh[nt], sb);
            sb = mfma16(kfh[1], qfl[nt], sb);
            sb = mfma16(kfl[1], qfh[nt], sb);
#pragma unroll
            for (int r = 0; r < 4; ++r) {
                float xa = sa[r];
                pah[nt][r] = f2bf(__builtin_amdgcn_cosf(xa - floorf(xa)));
                float xb2 = sb[r];
                pah[nt][r + 4] = f2bf(__builtin_amdgcn_cosf(xb2 - floorf(xb2)));
            }
        }
#pragma unroll
        for (int nt = 0; nt < 2; ++nt) {
            acc[nt][0] = mfma16(pah[nt], vf00, acc[nt][0]);
            acc[nt][0] = mfma16(pah[nt], vf01, acc[nt][0]);
            acc[nt][1] = mfma16(pah[nt], vf10, acc[nt][1]);
            acc[nt][1] = mfma16(pah[nt], vf11, acc[nt][1]);
        }
    }
    // epilogue: transpose through LDS, coalesced stores
#pragma unroll
    for (int nt = 0; nt < 2; ++nt)
#pragma unroll
        for (int dt = 0; dt < 2; ++dt)
#pragma unroll
            for (int r = 0; r < 4; ++r)
                st[w * 32 + nt * 16 + 4 * g + r][dt * 16 + r16] = acc[nt][dt][r];
    __syncthreads();
    const int tk = t >> 1, d0 = (t & 1) * 16;
    float* pbp = part + ((size_t)(s * NBATCH + b) * NTOK + nb * 128 + tk) * 32 + d0;
    const float* sp = &st[tk][d0];
#pragma unroll
    for (int q4 = 0; q4 < 4; ++q4)
        *(float4*)(pbp + q4 * 4) = *(const float4*)(sp + q4 * 4);
}

// ---------------------------------------------------------------------------
// Kernel D: fused reduce (sum 8 partials + coef*v via LDS) + ConvTranspose.
// 256 blocks x 512 thr.
// ---------------------------------------------------------------------------
__global__ __launch_bounds__(512) void k_deconv(
    const float* __restrict__ part, const float* __restrict__ vv,
    const float* __restrict__ coef, const float* __restrict__ dw,
    const float* __restrict__ db, float* __restrict__ out)
{
    __shared__ float inter_lds[64][33];
    const int tid  = threadIdx.x;
    const int bx   = blockIdx.x;
    const int b    = bx >> 6;
    const int hrow = bx & 63;

    {   // phase 1: reduce. thread = (token tk, d4)
        const int tk = tid >> 3, d4 = tid & 7;
        const int nn = hrow * 64 + tk;
        const size_t goff = ((size_t)(b * NTOK + nn)) * 32 + d4 * 4;
        float4 s = make_float4(0.f, 0.f, 0.f, 0.f);
#pragma unroll
        for (int sp = 0; sp < SPLIT; ++sp) {
            float4 t4 = *(const float4*)(part + (size_t)sp * (NBATCH * NTOK * 32) + goff);
            s.x += t4.x; s.y += t4.y; s.z += t4.z; s.w += t4.w;
        }
        const float cf = coef[b * NTOK + nn];
        float4 v4 = *(const float4*)(vv + goff);
        s.x += cf * v4.x; s.y += cf * v4.y; s.z += cf * v4.z; s.w += cf * v4.w;
        inter_lds[tk][d4 * 4 + 0] = s.x; inter_lds[tk][d4 * 4 + 1] = s.y;
        inter_lds[tk][d4 * 4 + 2] = s.z; inter_lds[tk][d4 * 4 + 3] = s.w;
    }
    __syncthreads();

    const int wv   = tid >> 6;     // 0..7, wave-uniform
    const int lane = tid & 63;     // token w
    float ir[32];
#pragma unroll
    for (int d = 0; d < 32; ++d) ir[d] = inter_lds[lane][d];
#pragma unroll
    for (int rr = 0; rr < 3; ++rr) {
        const int rho = wv * 3 + rr;      // 0..23, wave-uniform
        const int o = rho >> 3, p = rho & 7;
        const float bv = db[o];
        float a8[8];
#pragma unroll
        for (int q = 0; q < 8; ++q) a8[q] = bv;
        const float* wbase = dw + o * 64 + p * 8;
#pragma unroll
        for (int i = 0; i < 32; ++i) {
            float4 w0 = *(const float4*)(wbase + (size_t)i * 192);
            float4 w1 = *(const float4*)(wbase + (size_t)i * 192 + 4);
            const float iv = ir[i];
            a8[0] += iv * w0.x; a8[1] += iv * w0.y;
            a8[2] += iv * w0.z; a8[3] += iv * w0.w;
            a8[4] += iv * w1.x; a8[5] += iv * w1.y;
            a8[6] += iv * w1.z; a8[7] += iv * w1.w;
        }
        float* op = out + (((size_t)(b * 3 + o) * 512) + hrow * 8 + p) * 512 + lane * 8;
        *(float4*)op       = make_float4(a8[0], a8[1], a8[2], a8[3]);
        *(float4*)(op + 4) = make_float4(a8[4], a8[5], a8[6], a8[7]);
    }
}

// ---------------------------------------------------------------------------
extern "C" void kernel_launch(void* const* d_in, const int* in_sizes, int n_in,
                              void* d_out, int out_size, void* d_ws, size_t ws_size,
                              hipStream_t stream)
{
    const float* x  = (const float*)d_in[0];
    const float* cw = (const float*)d_in[1];
    const float* cb = (const float*)d_in[2];
    const float* pw = (const float*)d_in[3];
    const float* pb = (const float*)d_in[4];
    const float* dw = (const float*)d_in[5];
    const float* db = (const float*)d_in[6];
    float* out = (float*)d_out;

    char* wsb = (char*)d_ws;
    const size_t MB = 1u << 20;
    short* qh    = (short*)(wsb + 0 * MB);
    short* ql    = (short*)(wsb + 1 * MB);
    short* kh    = (short*)(wsb + 2 * MB);
    short* kl    = (short*)(wsb + 3 * MB);
    float* vv    = (float*)(wsb + 4 * MB);   // 2 MB
    short* varr  = (short*)(wsb + 6 * MB);   // 2 MB
    float* part  = (float*)(wsb + 8 * MB);   // 16 MB
    float* coef  = (float*)(wsb + 24 * MB);  // 64 KB

    hipLaunchKernelGGL(k_embed, dim3(256), dim3(256), 0, stream,
                       x, cw, cb, pw, pb, qh, ql, kh, kl, vv, coef, varr);
    hipLaunchKernelGGL(k_attn, dim3(1024), dim3(256), 0, stream,
                       qh, ql, kh, kl, varr, part);
    hipLaunchKernelGGL(k_deconv, dim3(256), dim3(512), 0, stream,
                       part, vv, coef, dw, db, out);
}